// Round 1
// baseline (464.232 us; speedup 1.0000x reference)
//
#include <hip/hip_runtime.h>
#include <math.h>

#define C_DIM 256
#define N_E   1024
#define ZQ_ELEMS 8388608
#define ZQ_OFF 1
#define PPLX_OFF (1 + ZQ_ELEMS)
#define IDX_OFF  (2 + ZQ_ELEMS)

// ws layout: [0] f32 loss accumulator, [1..1024] u32 counts

__global__ __launch_bounds__(256) void vq_zero(float* ws) {
    const int t = threadIdx.x;
    for (int i = t; i < 1025; i += 256) ws[i] = 0.0f;
}

// One block = 64 rows (one b, 64 consecutive hw). Full K=256 z-tile and
// per-64-entry codebook tiles staged transposed in LDS; 4x4 register tile
// per thread; fp32 fma chain in ascending-k order reproduces reference
// float32 rounding semantics. Argmin is lexicographic (d, j) min -> first
// index on ties, matching np.argmin.
__global__ __launch_bounds__(256) void vq_main(const float* __restrict__ z,
                                               const float* __restrict__ w,
                                               float* __restrict__ out,
                                               float* __restrict__ ws) {
    __shared__ float zt[C_DIM][64];   // [c][r]   64 KB
    __shared__ float wt[C_DIM][64];   // [k][j']  64 KB (reused as gather staging)
    __shared__ float sz2[64];
    __shared__ float sw2[64];
    __shared__ int   sjmin[64];
    __shared__ float lred[4];

    const int t   = threadIdx.x;
    const int n0  = blockIdx.x * 64;
    const int b   = n0 >> 10;
    const int hw0 = n0 & 1023;
    const int rg  = t >> 4;    // 0..15 row group (4 rows each)
    const int tg  = t & 15;    // 0..15 col group (4 cols each)

    // ---- stage z tile transposed: zt[c][r] ----
    {
        const int r4 = t & 15;
        const int cb = t >> 4;
        for (int i = 0; i < 16; ++i) {
            const int c = i * 16 + cb;
            float4 v = *(const float4*)(z + ((size_t)(b * C_DIM + c) << 10) + hw0 + r4 * 4);
            *(float4*)&zt[c][r4 * 4] = v;
        }
    }
    __syncthreads();

    // ---- z2 per row (fp32, ascending k) ----
    if (t < 64) {
        float s = 0.0f;
        for (int k = 0; k < C_DIM; ++k) { float v = zt[k][t]; s = fmaf(v, v, s); }
        sz2[t] = s;
    }
    __syncthreads();

    float z2r[4];
    for (int m = 0; m < 4; ++m) z2r[m] = sz2[rg * 4 + m];

    float dbest[4];
    int   jbest[4];
    for (int m = 0; m < 4; ++m) { dbest[m] = INFINITY; jbest[m] = 0; }

    for (int jt = 0; jt < 16; ++jt) {
        // stage w tile transposed: wt[k][j']  (j' = lane -> conflict-free LDS writes)
        {
            const int jp = t & 63;
            const int kq = t >> 6;   // 0..3
            const float* wrow = w + ((size_t)(jt * 64 + jp) << 8);
            for (int i = 0; i < 16; ++i) {
                const int k4 = i * 4 + kq;   // 0..63
                float4 v = *(const float4*)(wrow + k4 * 4);
                wt[k4 * 4 + 0][jp] = v.x;
                wt[k4 * 4 + 1][jp] = v.y;
                wt[k4 * 4 + 2][jp] = v.z;
                wt[k4 * 4 + 3][jp] = v.w;
            }
        }
        __syncthreads();

        // w2 for this tile (wave 0, overlapped with other waves' K-loop)
        if (t < 64) {
            float s = 0.0f;
            for (int k = 0; k < C_DIM; ++k) { float v = wt[k][t]; s = fmaf(v, v, s); }
            sw2[t] = s;
        }

        float acc[4][4];
        for (int m = 0; m < 16; ++m) ((float*)acc)[m] = 0.0f;

        #pragma unroll 8
        for (int k = 0; k < C_DIM; ++k) {
            float4 av = *(const float4*)&zt[k][rg * 4];
            float4 bv = *(const float4*)&wt[k][tg * 4];
            const float a0 = av.x, a1 = av.y, a2 = av.z, a3 = av.w;
            const float b0 = bv.x, b1 = bv.y, b2 = bv.z, b3 = bv.w;
            acc[0][0] = fmaf(a0, b0, acc[0][0]); acc[0][1] = fmaf(a0, b1, acc[0][1]);
            acc[0][2] = fmaf(a0, b2, acc[0][2]); acc[0][3] = fmaf(a0, b3, acc[0][3]);
            acc[1][0] = fmaf(a1, b0, acc[1][0]); acc[1][1] = fmaf(a1, b1, acc[1][1]);
            acc[1][2] = fmaf(a1, b2, acc[1][2]); acc[1][3] = fmaf(a1, b3, acc[1][3]);
            acc[2][0] = fmaf(a2, b0, acc[2][0]); acc[2][1] = fmaf(a2, b1, acc[2][1]);
            acc[2][2] = fmaf(a2, b2, acc[2][2]); acc[2][3] = fmaf(a2, b3, acc[2][3]);
            acc[3][0] = fmaf(a3, b0, acc[3][0]); acc[3][1] = fmaf(a3, b1, acc[3][1]);
            acc[3][2] = fmaf(a3, b2, acc[3][2]); acc[3][3] = fmaf(a3, b3, acc[3][3]);
        }
        __syncthreads();   // sw2 ready; wt free for next tile

        // combine per reference semantics: d = fl(fl(z2 + w2) - 2*dot)
        for (int c = 0; c < 4; ++c) {
            const int   j  = jt * 64 + tg * 4 + c;
            const float w2 = sw2[tg * 4 + c];
            for (int m = 0; m < 4; ++m) {
                const float u = z2r[m] + w2;
                const float d = u - 2.0f * acc[m][c];
                if (d < dbest[m]) { dbest[m] = d; jbest[m] = j; }  // ascending j: strict <
            }
        }
    }

    // ---- lexicographic (d, j) min across the 16 col-group lanes ----
    for (int m = 0; m < 4; ++m) {
        float d = dbest[m];
        int   j = jbest[m];
        for (int off = 8; off >= 1; off >>= 1) {
            float od = __shfl_xor(d, off, 16);
            int   oj = __shfl_xor(j, off, 16);
            if (od < d || (od == d && oj < j)) { d = od; j = oj; }
        }
        if (tg == 0) sjmin[rg * 4 + m] = j;
    }
    __syncthreads();

    // ---- indices + counts ----
    if (t < 64) {
        const int j = sjmin[t];
        out[IDX_OFF + n0 + t] = (float)j;
        atomicAdd((unsigned int*)ws + 1 + j, 1u);
    }

    // ---- gather codebook rows, accumulate loss, stage transposed into wt ----
    float lsum = 0.0f;
    {
        const int r  = t & 63;
        const int cq = t >> 6;
        const float* wrow = w + ((size_t)sjmin[r] << 8);
        for (int i = 0; i < 16; ++i) {
            const int c4 = i * 4 + cq;
            float4 v = *(const float4*)(wrow + c4 * 4);
            const int c0 = c4 * 4;
            float d0 = v.x - zt[c0 + 0][r];
            float d1 = v.y - zt[c0 + 1][r];
            float d2 = v.z - zt[c0 + 2][r];
            float d3 = v.w - zt[c0 + 3][r];
            lsum += d0 * d0 + d1 * d1 + d2 * d2 + d3 * d3;
            wt[c0 + 0][r] = v.x;
            wt[c0 + 1][r] = v.y;
            wt[c0 + 2][r] = v.z;
            wt[c0 + 3][r] = v.w;
        }
    }
    __syncthreads();

    // ---- write z_q (NCHW) coalesced ----
    {
        const int r4 = t & 15;
        const int cb = t >> 4;
        for (int i = 0; i < 16; ++i) {
            const int c = i * 16 + cb;
            float4 v = *(const float4*)&wt[c][r4 * 4];
            *(float4*)(out + ZQ_OFF + ((size_t)(b * C_DIM + c) << 10) + hw0 + r4 * 4) = v;
        }
    }

    // ---- loss partial -> one atomic per block ----
    for (int off = 32; off >= 1; off >>= 1) lsum += __shfl_xor(lsum, off, 64);
    if ((t & 63) == 0) lred[t >> 6] = lsum;
    __syncthreads();
    if (t == 0) atomicAdd(ws, lred[0] + lred[1] + lred[2] + lred[3]);
}

__global__ __launch_bounds__(1024) void vq_fin(float* __restrict__ out,
                                               float* __restrict__ ws) {
    __shared__ float red[16];
    const int t = threadIdx.x;
    const unsigned cnt = ((const unsigned int*)ws)[1 + t];
    const float e = (float)cnt * (1.0f / 32768.0f);
    float s = e * logf(e + 1e-10f);
    for (int off = 32; off >= 1; off >>= 1) s += __shfl_xor(s, off, 64);
    if ((t & 63) == 0) red[t >> 6] = s;
    __syncthreads();
    if (t == 0) {
        float H = 0.0f;
        for (int i = 0; i < 16; ++i) H += red[i];
        out[PPLX_OFF] = expf(-H);
        const float l = ws[0] * (1.0f / 8388608.0f);
        out[0] = l + 0.25f * l;   // mean + BETA*mean
    }
}

extern "C" void kernel_launch(void* const* d_in, const int* in_sizes, int n_in,
                              void* d_out, int out_size, void* d_ws, size_t ws_size,
                              hipStream_t stream) {
    const float* z = (const float*)d_in[0];   // (32,256,32,32) f32
    const float* w = (const float*)d_in[1];   // (1024,256) f32
    float* out = (float*)d_out;
    float* ws  = (float*)d_ws;

    vq_zero<<<1, 256, 0, stream>>>(ws);
    vq_main<<<512, 256, 0, stream>>>(z, w, out, ws);
    vq_fin<<<1, 1024, 0, stream>>>(out, ws);
}

// Round 2
// 363.338 us; speedup vs baseline: 1.2777x; 1.2777x over previous
//
#include <hip/hip_runtime.h>
#include <math.h>

#define ZQ_ELEMS 8388608
#define ZQ_OFF 1
#define PPLX_OFF (1 + ZQ_ELEMS)
#define IDX_OFF  (2 + ZQ_ELEMS)

typedef __attribute__((ext_vector_type(8))) short short8;
typedef __attribute__((ext_vector_type(4))) float f32x4;

// ---- ws byte layout ----
// 0        : loss f32
// 256      : counts u32[1024]          (perplexity histogram)
// 8192     : candc u32[32768]          (append counters, zeroed)
// 139264   : flagv u32[32768]          (fallback flag, written every launch)
// 270336   : lists u16[32768*24]       (candidate j lists)
// 1843200  : w2 f32[1024]
// 1847296  : ebf bf16[1024*256]        (codebook in bf16)
#define WS_CANDC 8192
#define WS_FLAG  139264
#define WS_LIST  270336
#define WS_W2    1843200
#define WS_EBF   1847296

static __device__ __forceinline__ ushort f2bf(float f) {
    uint u = __float_as_uint(f);
    return (ushort)((u + 0x7fffu + ((u >> 16) & 1u)) >> 16);
}

__global__ __launch_bounds__(256) void vq_zero(uint* ws) {
    // zero words 0..34816 (loss, counts, candc)
    for (int i = blockIdx.x * 256 + threadIdx.x; i < 34816; i += 64 * 256) ws[i] = 0u;
}

__global__ __launch_bounds__(256) void vq_prep_e(const float* __restrict__ w,
                                                 ushort* __restrict__ ebf,
                                                 float* __restrict__ w2) {
    const int j = blockIdx.x * 256 + threadIdx.x;   // 4 blocks -> 1024
    const float* wr = w + (size_t)j * 256;
    float s = 0.f;
    for (int k = 0; k < 256; k += 2) {
        float f0 = wr[k], f1 = wr[k + 1];
        s = fmaf(f0, f0, s);
        s = fmaf(f1, f1, s);            // ascending-k chain (matches refine's w2 use)
        ((uint*)ebf)[((size_t)j * 256 + k) >> 1] = (uint)f2bf(f0) | ((uint)f2bf(f1) << 16);
    }
    w2[j] = s;
}

// K1: bf16 MFMA approximate sweep. 512 blocks x 256thr; wave = 16 rows; all 1024 j.
__global__ __launch_bounds__(256) void vq_sweep(const float* __restrict__ z,
                                                const ushort* __restrict__ ebf,
                                                const float* __restrict__ w2,
                                                uint* __restrict__ candc,
                                                uint* __restrict__ flagv,
                                                ushort* __restrict__ lists) {
    __shared__ float sz2a[64];
    const int t = threadIdx.x;
    const int wv = t >> 6;
    const int l = t & 63;
    const int l15 = l & 15, lg = l >> 4;          // lg 0..3
    const int n0 = blockIdx.x * 64 + wv * 16;     // this wave's 16 rows
    const int b = n0 >> 10, hw0 = n0 & 1023;

    // ---- load A fragments (16 rows x 256 k) into registers, bf16 ----
    short8 a[8];
    float z2p = 0.f;
    const float* zb = z + (size_t)b * (256 * 1024) + hw0 + l15;  // z[b][k][hw0+l15]
    #pragma unroll
    for (int s = 0; s < 8; ++s) {
        short8 fr;
        #pragma unroll
        for (int i = 0; i < 8; ++i) {
            const int k = s * 32 + lg * 8 + i;
            float f = zb[(size_t)k << 10];
            z2p = fmaf(f, f, z2p);
            fr[i] = (short)f2bf(f);
        }
        a[s] = fr;
    }
    // approx ||z||^2 per row (lanes l15, l15+16, +32, +48 hold row n0+l15's pieces)
    z2p += __shfl_xor(z2p, 16);
    z2p += __shfl_xor(z2p, 32);
    if (lg == 0) sz2a[wv * 16 + l15] = z2p;
    __syncthreads();

    float Tr[4], rm[4];
    #pragma unroll
    for (int r = 0; r < 4; ++r) {
        Tr[r] = -2.617e-3f * sqrtf(sz2a[wv * 16 + 4 * lg + r]);  // -2.32 sigma of score
        rm[r] = 1e30f;
    }
    const float MARGIN = 1.5e-3f;

    for (int jg = 0; jg < 32; ++jg) {
        const int j0 = jg * 32;
        const ushort* e0 = ebf + (size_t)(j0 + l15) * 256 + lg * 8;
        const ushort* e1 = e0 + 16 * 256;
        short8 b0[8], b1[8];
        #pragma unroll
        for (int s = 0; s < 8; ++s) {
            b0[s] = *(const short8*)(e0 + s * 32);
            b1[s] = *(const short8*)(e1 + s * 32);
        }
        f32x4 acc0 = {0.f, 0.f, 0.f, 0.f};
        f32x4 acc1 = {0.f, 0.f, 0.f, 0.f};
        #pragma unroll
        for (int s = 0; s < 8; ++s) {
            acc0 = __builtin_amdgcn_mfma_f32_16x16x32_bf16(a[s], b0[s], acc0, 0, 0, 0);
            acc1 = __builtin_amdgcn_mfma_f32_16x16x32_bf16(a[s], b1[s], acc1, 0, 0, 0);
        }
        const float w2a = w2[j0 + l15];
        const float w2b = w2[j0 + 16 + l15];
        float sv[2][4];
        bool pv[2][4];
        bool anyp = false;
        #pragma unroll
        for (int r = 0; r < 4; ++r) {
            sv[0][r] = fmaf(-2.f, acc0[r], w2a);
            sv[1][r] = fmaf(-2.f, acc1[r], w2b);
            pv[0][r] = sv[0][r] <= Tr[r];
            pv[1][r] = sv[1][r] <= Tr[r];
            anyp = anyp || pv[0][r] || pv[1][r];
            rm[r] = fminf(rm[r], fminf(sv[0][r], sv[1][r]));
        }
        if (__any(anyp)) {
            #pragma unroll
            for (int jt = 0; jt < 2; ++jt)
                #pragma unroll
                for (int r = 0; r < 4; ++r)
                    if (pv[jt][r]) {
                        const int n = n0 + 4 * lg + r;
                        uint pos = atomicAdd(&candc[n], 1u);
                        if (pos < 24u) lists[(size_t)n * 24 + pos] = (ushort)(j0 + jt * 16 + l15);
                    }
        }
    }

    // reduce rm across the 16 lanes sharing each row group
    #pragma unroll
    for (int off = 1; off < 16; off <<= 1)
        #pragma unroll
        for (int r = 0; r < 4; ++r) rm[r] = fminf(rm[r], __shfl_xor(rm[r], off));
    if (l15 == 0) {
        #pragma unroll
        for (int r = 0; r < 4; ++r)
            flagv[n0 + 4 * lg + r] = (rm[r] > Tr[r] - MARGIN) ? 1u : 0u;
    }
}

// K2: exact fp32 refine (bitwise round-1 chain) + epilogue. 512 blocks x 256thr, 64 rows each.
__global__ __launch_bounds__(256) void vq_refine(const float* __restrict__ z,
                                                 const float* __restrict__ w,
                                                 const float* __restrict__ w2,
                                                 const uint* __restrict__ candc,
                                                 const uint* __restrict__ flagv,
                                                 const ushort* __restrict__ lists,
                                                 float* __restrict__ out,
                                                 float* __restrict__ ws) {
    __shared__ float tile[256][64];    // z transposed, later gathered codebook rows
    __shared__ float sz2[64];
    __shared__ int sjmin[64];
    __shared__ int scnt[64];
    __shared__ int soff[65];
    __shared__ uint swl[1536];
    __shared__ float sd[1536];
    __shared__ unsigned long long sfbm;
    __shared__ unsigned long long sred[4];
    __shared__ float lred[4];

    const int t = threadIdx.x;
    const int n0 = blockIdx.x * 64;
    const int b = n0 >> 10, hw0 = n0 & 1023;

    if (t == 0) sfbm = 0ull;

    // ---- stage z tile transposed ----
    {
        const int r4 = t & 15, cb = t >> 4;
        for (int i = 0; i < 16; ++i) {
            const int c = i * 16 + cb;
            float4 v = *(const float4*)(z + ((size_t)(b * 256 + c) << 10) + hw0 + r4 * 4);
            *(float4*)&tile[c][r4 * 4] = v;
        }
    }
    __syncthreads();

    // ---- exact z2 (ascending k, round-1 chain) ----
    if (t < 64) {
        float s = 0.f;
        for (int k = 0; k < 256; ++k) { float v = tile[k][t]; s = fmaf(v, v, s); }
        sz2[t] = s;
    }
    // ---- candidate setup ----
    if (t < 64) {
        const int n = n0 + t;
        uint c = candc[n];
        bool fb = (flagv[n] != 0u) || (c == 0u) || (c > 24u);
        scnt[t] = fb ? 0 : (int)c;
        if (fb) atomicOr(&sfbm, 1ull << t);
    }
    __syncthreads();
    if (t == 0) {
        int acc = 0;
        for (int r = 0; r < 64; ++r) { soff[r] = acc; acc += scnt[r]; }
        soff[64] = acc;
    }
    __syncthreads();
    if (t < 64) {
        const int o = soff[t], c = scnt[t], n = n0 + t;
        for (int i = 0; i < c; ++i) swl[o + i] = ((uint)t << 16) | (uint)lists[(size_t)n * 24 + i];
    }
    __syncthreads();

    // ---- exact evaluation of candidates (ascending-k fmaf, identical to round-1) ----
    const int total = soff[64];
    for (int e = t; e < total; e += 256) {
        const int r = (int)(swl[e] >> 16);
        const int j = (int)(swl[e] & 0xffffu);
        const float* wr = w + ((size_t)j << 8);
        float dot = 0.f;
        for (int k4 = 0; k4 < 64; ++k4) {
            float4 v = *(const float4*)(wr + k4 * 4);
            const int k0 = k4 * 4;
            dot = fmaf(v.x, tile[k0 + 0][r], dot);
            dot = fmaf(v.y, tile[k0 + 1][r], dot);
            dot = fmaf(v.z, tile[k0 + 2][r], dot);
            dot = fmaf(v.w, tile[k0 + 3][r], dot);
        }
        const float u = sz2[r] + w2[j];
        sd[e] = u - 2.0f * dot;
    }
    __syncthreads();

    // ---- per-row lexicographic (d, j) argmin over candidates ----
    if (t < 64 && scnt[t] > 0) {
        float db = 1e30f; int jb = 0;
        const int o = soff[t], c = scnt[t];
        for (int i = 0; i < c; ++i) {
            float d = sd[o + i];
            int j = (int)(swl[o + i] & 0xffffu);
            if (d < db || (d == db && j < jb)) { db = d; jb = j; }
        }
        sjmin[t] = jb;
    }
    __syncthreads();

    // ---- fallback rows: full exact scan over all 1024 j, block-wide ----
    unsigned long long fm = sfbm;
    while (fm) {
        const int r = __ffsll(fm) - 1;
        fm &= fm - 1;
        unsigned long long key = ~0ull;
        for (int jj = 0; jj < 4; ++jj) {
            const int j = t * 4 + jj;
            const float* wr = w + ((size_t)j << 8);
            float dot = 0.f;
            for (int k4 = 0; k4 < 64; ++k4) {
                float4 v = *(const float4*)(wr + k4 * 4);
                const int k0 = k4 * 4;
                dot = fmaf(v.x, tile[k0 + 0][r], dot);
                dot = fmaf(v.y, tile[k0 + 1][r], dot);
                dot = fmaf(v.z, tile[k0 + 2][r], dot);
                dot = fmaf(v.w, tile[k0 + 3][r], dot);
            }
            const float u = sz2[r] + w2[j];
            const float d = u - 2.0f * dot;
            unsigned long long kk = ((unsigned long long)__float_as_uint(d) << 32) | (uint)j;
            if (kk < key) key = kk;
        }
        #pragma unroll
        for (int off = 32; off >= 1; off >>= 1) {
            unsigned long long ok = __shfl_xor(key, off);
            if (ok < key) key = ok;
        }
        if ((t & 63) == 0) sred[t >> 6] = key;
        __syncthreads();
        if (t == 0) {
            unsigned long long kk = sred[0];
            for (int i = 1; i < 4; ++i) if (sred[i] < kk) kk = sred[i];
            sjmin[r] = (int)(kk & 0xffffffffull);
        }
        __syncthreads();
    }
    __syncthreads();

    // ---- indices + perplexity counts ----
    if (t < 64) {
        const int j = sjmin[t];
        out[IDX_OFF + n0 + t] = (float)j;
        atomicAdd((uint*)ws + 64 + j, 1u);
    }

    // ---- gather codebook rows, loss, stage into tile (in-place) ----
    float lsum = 0.f;
    {
        const int r = t & 63, cq = t >> 6;
        const float* wrow = w + ((size_t)sjmin[r] << 8);
        for (int i = 0; i < 16; ++i) {
            const int c0 = (i * 4 + cq) * 4;
            float4 v = *(const float4*)(wrow + c0);
            float d0 = v.x - tile[c0 + 0][r];
            float d1 = v.y - tile[c0 + 1][r];
            float d2 = v.z - tile[c0 + 2][r];
            float d3 = v.w - tile[c0 + 3][r];
            lsum += d0 * d0 + d1 * d1 + d2 * d2 + d3 * d3;
            tile[c0 + 0][r] = v.x;
            tile[c0 + 1][r] = v.y;
            tile[c0 + 2][r] = v.z;
            tile[c0 + 3][r] = v.w;
        }
    }
    __syncthreads();

    // ---- z_q (NCHW) coalesced write ----
    {
        const int r4 = t & 15, cb = t >> 4;
        for (int i = 0; i < 16; ++i) {
            const int c = i * 16 + cb;
            float4 v = *(const float4*)&tile[c][r4 * 4];
            *(float4*)(out + ZQ_OFF + ((size_t)(b * 256 + c) << 10) + hw0 + r4 * 4) = v;
        }
    }

    // ---- loss reduction ----
    for (int off = 32; off >= 1; off >>= 1) lsum += __shfl_xor(lsum, off, 64);
    if ((t & 63) == 0) lred[t >> 6] = lsum;
    __syncthreads();
    if (t == 0) atomicAdd(ws, lred[0] + lred[1] + lred[2] + lred[3]);
}

__global__ __launch_bounds__(1024) void vq_fin(float* __restrict__ out,
                                               float* __restrict__ ws) {
    __shared__ float red[16];
    const int t = threadIdx.x;
    const uint cnt = ((const uint*)ws)[64 + t];
    const float e = (float)cnt * (1.0f / 32768.0f);
    float s = e * logf(e + 1e-10f);
    for (int off = 32; off >= 1; off >>= 1) s += __shfl_xor(s, off, 64);
    if ((t & 63) == 0) red[t >> 6] = s;
    __syncthreads();
    if (t == 0) {
        float H = 0.f;
        for (int i = 0; i < 16; ++i) H += red[i];
        out[PPLX_OFF] = expf(-H);
        const float l = ws[0] * (1.0f / 8388608.0f);
        out[0] = l + 0.25f * l;
    }
}

extern "C" void kernel_launch(void* const* d_in, const int* in_sizes, int n_in,
                              void* d_out, int out_size, void* d_ws, size_t ws_size,
                              hipStream_t stream) {
    const float* z = (const float*)d_in[0];   // (32,256,32,32) f32
    const float* w = (const float*)d_in[1];   // (1024,256) f32
    float* out = (float*)d_out;
    float* ws = (float*)d_ws;

    uint* candc = (uint*)((char*)d_ws + WS_CANDC);
    uint* flagv = (uint*)((char*)d_ws + WS_FLAG);
    ushort* lists = (ushort*)((char*)d_ws + WS_LIST);
    float* w2 = (float*)((char*)d_ws + WS_W2);
    ushort* ebf = (ushort*)((char*)d_ws + WS_EBF);

    vq_zero<<<64, 256, 0, stream>>>((uint*)d_ws);
    vq_prep_e<<<4, 256, 0, stream>>>(w, ebf, w2);
    vq_sweep<<<512, 256, 0, stream>>>(z, ebf, w2, candc, flagv, lists);
    vq_refine<<<512, 256, 0, stream>>>(z, w, w2, candc, flagv, lists, out, ws);
    vq_fin<<<1, 1024, 0, stream>>>(out, ws);
}

// Round 4
// 250.779 us; speedup vs baseline: 1.8512x; 1.4488x over previous
//
#include <hip/hip_runtime.h>
#include <math.h>

#define ZQ_ELEMS 8388608
#define ZQ_OFF 1
#define PPLX_OFF (1 + ZQ_ELEMS)
#define IDX_OFF  (2 + ZQ_ELEMS)

typedef __attribute__((ext_vector_type(8))) short short8;
typedef __attribute__((ext_vector_type(4))) float f32x4;
typedef __attribute__((ext_vector_type(16))) float f32x16;

// ---- ws byte layout (2.37 MB total, same footprint as round 2) ----
// 0       : loss f32
// 256     : counts u32[1024]
// 8192    : candc u32[32768]      (zeroed)
// 139264  : safeflag u32[32768]   (zeroed; 1 = row has approx score <= Tr-MARGIN)
// 270336  : lists u16[32768*24]
// 1843200 : w2 f32[1024]
// 1847296 : ebf_l ushort[262144]  codebook bf16 in MFMA fragment layout
#define WS_CANDC 8192
#define WS_FLAG  139264
#define WS_LIST  270336
#define WS_W2    1843200
#define WS_EBF   1847296

static __device__ __forceinline__ ushort f2bf(float f) {
    uint u = __float_as_uint(f);
    return (ushort)((u + 0x7fffu + ((u >> 16) & 1u)) >> 16);
}

__global__ __launch_bounds__(256) void vq_zero(uint* ws) {
    // zero bytes [0, 270336): loss, counts, candc, safeflag
    for (int i = blockIdx.x * 256 + threadIdx.x; i < 67584; i += 64 * 256) ws[i] = 0u;
}

// exact ||e_j||^2, ascending-k fmaf chain (bitwise identical to rounds 1/2)
__global__ __launch_bounds__(64) void vq_prep_w2(const float* __restrict__ w,
                                                 float* __restrict__ w2) {
    const int j = blockIdx.x * 64 + threadIdx.x;   // 16 blocks
    const float* wr = w + (size_t)j * 256;
    float s = 0.f;
    for (int k4 = 0; k4 < 64; ++k4) {
        float4 v = *(const float4*)(wr + k4 * 4);
        s = fmaf(v.x, v.x, s); s = fmaf(v.y, v.y, s);
        s = fmaf(v.z, v.z, s); s = fmaf(v.w, v.w, s);
    }
    w2[j] = s;
}

// codebook -> bf16 in 32x32x16-MFMA B-fragment layout:
// ebf_l[jt=j>>5][s=k>>4][lane=(j&31)+32*((k>>3)&1)][i=k&7]
__global__ __launch_bounds__(256) void vq_prep_e(const float* __restrict__ w,
                                                 ushort* __restrict__ ebf_l) {
    const int g = blockIdx.x * 256 + threadIdx.x;   // 128 blocks -> 32768 chunks
    const int j = g >> 5, o = g & 31;               // o = k-octet
    const float* src = w + (size_t)j * 256 + o * 8;
    float4 v0 = *(const float4*)src;
    float4 v1 = *(const float4*)(src + 4);
    short8 r;
    r[0] = (short)f2bf(v0.x); r[1] = (short)f2bf(v0.y);
    r[2] = (short)f2bf(v0.z); r[3] = (short)f2bf(v0.w);
    r[4] = (short)f2bf(v1.x); r[5] = (short)f2bf(v1.y);
    r[6] = (short)f2bf(v1.z); r[7] = (short)f2bf(v1.w);
    const size_t dst = (size_t)(j >> 5) * 8192 + (size_t)(o >> 1) * 512
                     + (size_t)((j & 31) + (o & 1) * 32) * 8;   // ushort units
    *(short8*)(ebf_l + dst) = r;
}

// K1: bf16 32x32x16-MFMA approx sweep. grid 1024 = 256 row-blocks x 4 j-quarters.
// Wave = 32 rows x 256 j. Appends buffered in LDS; one global atomic per row at flush.
__global__ __launch_bounds__(256) void vq_sweep(const float* __restrict__ z,
                                                const ushort* __restrict__ ebf_l,
                                                const float* __restrict__ w2,
                                                uint* __restrict__ candc,
                                                uint* __restrict__ safeflag,
                                                ushort* __restrict__ lists) {
    __shared__ ushort lcl[128][16];
    __shared__ uint lcnt[128];
    __shared__ float sTr[128];

    const int t = threadIdx.x, wv = t >> 6, l = t & 63;
    const int jq = blockIdx.x & 3, rb = blockIdx.x >> 2;
    const int n0 = rb * 128 + wv * 32;              // wave's first row
    const int b = n0 >> 10, hw0 = n0 & 1023;        // 32-row tile never crosses b
    const int lj = l & 31, hi = l >> 5;

    for (int i = t; i < 128; i += 256) lcnt[i] = 0u;

    // ---- A fragments (32 rows x 256 k) + approx ||z||^2 ----
    const float* zb = z + (size_t)b * 262144 + hw0 + lj;
    short8 as[16];
    float z2p = 0.f;
    #pragma unroll
    for (int s = 0; s < 16; ++s) {
        short8 fr;
        #pragma unroll
        for (int i = 0; i < 8; ++i) {
            const int k = s * 16 + hi * 8 + i;
            float f = zb[(size_t)k << 10];
            z2p = fmaf(f, f, z2p);
            fr[i] = (short)f2bf(f);
        }
        as[s] = fr;
    }
    z2p += __shfl_xor(z2p, 32);
    if (hi == 0) sTr[wv * 32 + lj] = -2.617e-3f * sqrtf(z2p);  // -2.32 sigma
    __syncthreads();

    int rloc[16];
    float TrW[16];
    #pragma unroll
    for (int q = 0; q < 16; ++q) {
        rloc[q] = wv * 32 + (q & 3) + 8 * (q >> 2) + 4 * hi;   // C-row of acc[q]
        TrW[q] = sTr[rloc[q]];
    }

    const int jbase = jq * 256;
    float w2v[8];
    #pragma unroll
    for (int g = 0; g < 8; ++g) w2v[g] = w2[jbase + g * 32 + lj];

    uint safem = 0u;
    for (int g = 0; g < 8; ++g) {
        const ushort* bt = ebf_l + (size_t)(jq * 8 + g) * 8192;
        f32x16 acc = {};
        #pragma unroll
        for (int s = 0; s < 16; ++s) {
            short8 bf = *(const short8*)(bt + s * 512 + l * 8);
            acc = __builtin_amdgcn_mfma_f32_32x32x16_bf16(as[s], bf, acc, 0, 0, 0);
        }
        const int j = jbase + g * 32 + lj;
        float sv[16];
        bool anyhit = false;
        #pragma unroll
        for (int q = 0; q < 16; ++q) {
            sv[q] = fmaf(-2.f, acc[q], w2v[g]);
            anyhit = anyhit || (sv[q] <= TrW[q]);
        }
        if (__any(anyhit)) {
            #pragma unroll
            for (int q = 0; q < 16; ++q)
                if (sv[q] <= TrW[q]) {
                    uint pos = atomicAdd(&lcnt[rloc[q]], 1u);
                    if (pos < 16u) lcl[rloc[q]][pos] = (ushort)j;
                    if (sv[q] <= TrW[q] - 1.5e-3f) safem |= (1u << q);
                }
        }
    }

    // OR safety bits across the 32 lanes of each half-wave (rows fixed per half)
    #pragma unroll
    for (int off = 1; off < 32; off <<= 1) safem |= __shfl_xor(safem, off);
    if (lj == 0) {
        #pragma unroll
        for (int q = 0; q < 16; ++q)
            if (safem & (1u << q)) safeflag[rb * 128 + rloc[q]] = 1u;  // benign race
    }
    __syncthreads();

    // ---- flush LDS lists to global (one atomic per row) ----
    if (t < 128) {
        const uint lc = lcnt[t];
        const int n = rb * 128 + t;
        if (lc > 16u) atomicAdd(&candc[n], 100u);       // local overflow -> force fallback
        else if (lc) {
            uint base = atomicAdd(&candc[n], lc);
            for (uint i = 0; i < lc && base + i < 24u; ++i)
                lists[(size_t)n * 24 + base + i] = lcl[t][i];
        }
    }
}

// K2: exact fp32 refine (bitwise round-1/2 chain) + epilogue. 512 blocks, 64 rows each.
__global__ __launch_bounds__(256) void vq_refine(const float* __restrict__ z,
                                                 const float* __restrict__ w,
                                                 const float* __restrict__ w2,
                                                 const uint* __restrict__ candc,
                                                 const uint* __restrict__ safeflag,
                                                 const ushort* __restrict__ lists,
                                                 float* __restrict__ out,
                                                 float* __restrict__ ws) {
    __shared__ float tile[256][64];
    __shared__ float sz2[64];
    __shared__ int sjmin[64];
    __shared__ int scnt[64];
    __shared__ int soff[65];
    __shared__ uint swl[1536];
    __shared__ float sd[1536];
    __shared__ unsigned long long sfbm;
    __shared__ unsigned long long sred[4];
    __shared__ float lred[4];

    const int t = threadIdx.x;
    const int n0 = blockIdx.x * 64;
    const int b = n0 >> 10, hw0 = n0 & 1023;

    if (t == 0) sfbm = 0ull;

    {   // stage z tile transposed
        const int r4 = t & 15, cb = t >> 4;
        for (int i = 0; i < 16; ++i) {
            const int c = i * 16 + cb;
            float4 v = *(const float4*)(z + ((size_t)(b * 256 + c) << 10) + hw0 + r4 * 4);
            *(float4*)&tile[c][r4 * 4] = v;
        }
    }
    __syncthreads();

    // exact z2 (ascending k)
    if (t < 64) {
        float s = 0.f;
        for (int k = 0; k < 256; ++k) { float v = tile[k][t]; s = fmaf(v, v, s); }
        sz2[t] = s;
    }
    // candidate setup
    if (t < 64) {
        const int n = n0 + t;
        uint c = candc[n];
        bool fb = (safeflag[n] == 0u) || (c == 0u) || (c > 24u);
        scnt[t] = fb ? 0 : (int)c;
        if (fb) atomicOr(&sfbm, 1ull << t);
    }
    __syncthreads();
    if (t == 0) {
        int acc = 0;
        for (int r = 0; r < 64; ++r) { soff[r] = acc; acc += scnt[r]; }
        soff[64] = acc;
    }
    __syncthreads();
    if (t < 64) {
        const int o = soff[t], c = scnt[t], n = n0 + t;
        for (int i = 0; i < c; ++i) swl[o + i] = ((uint)t << 16) | (uint)lists[(size_t)n * 24 + i];
    }
    __syncthreads();

    // exact candidate evaluation (ascending-k fmaf, round-1 chain)
    const int total = soff[64];
    for (int e = t; e < total; e += 256) {
        const int r = (int)(swl[e] >> 16);
        const int j = (int)(swl[e] & 0xffffu);
        const float* wr = w + ((size_t)j << 8);
        float dot = 0.f;
        for (int k4 = 0; k4 < 64; ++k4) {
            float4 v = *(const float4*)(wr + k4 * 4);
            const int k0 = k4 * 4;
            dot = fmaf(v.x, tile[k0 + 0][r], dot);
            dot = fmaf(v.y, tile[k0 + 1][r], dot);
            dot = fmaf(v.z, tile[k0 + 2][r], dot);
            dot = fmaf(v.w, tile[k0 + 3][r], dot);
        }
        const float u = sz2[r] + w2[j];
        sd[e] = u - 2.0f * dot;
    }
    __syncthreads();

    // per-row lexicographic (d, j) argmin
    if (t < 64 && scnt[t] > 0) {
        float db = 1e30f; int jb = 0;
        const int o = soff[t], c = scnt[t];
        for (int i = 0; i < c; ++i) {
            float d = sd[o + i];
            int j = (int)(swl[o + i] & 0xffffu);
            if (d < db || (d == db && j < jb)) { db = d; jb = j; }
        }
        sjmin[t] = jb;
    }
    __syncthreads();

    // fallback rows: full exact block-wide scan
    unsigned long long fm = sfbm;
    while (fm) {
        const int r = __ffsll(fm) - 1;
        fm &= fm - 1;
        unsigned long long key = ~0ull;
        for (int jj = 0; jj < 4; ++jj) {
            const int j = t * 4 + jj;
            const float* wr = w + ((size_t)j << 8);
            float dot = 0.f;
            for (int k4 = 0; k4 < 64; ++k4) {
                float4 v = *(const float4*)(wr + k4 * 4);
                const int k0 = k4 * 4;
                dot = fmaf(v.x, tile[k0 + 0][r], dot);
                dot = fmaf(v.y, tile[k0 + 1][r], dot);
                dot = fmaf(v.z, tile[k0 + 2][r], dot);
                dot = fmaf(v.w, tile[k0 + 3][r], dot);
            }
            const float u = sz2[r] + w2[j];
            const float d = u - 2.0f * dot;
            unsigned long long kk = ((unsigned long long)__float_as_uint(d) << 32) | (uint)j;
            if (kk < key) key = kk;
        }
        #pragma unroll
        for (int off = 32; off >= 1; off >>= 1) {
            unsigned long long ok = __shfl_xor(key, off);
            if (ok < key) key = ok;
        }
        if ((t & 63) == 0) sred[t >> 6] = key;
        __syncthreads();
        if (t == 0) {
            unsigned long long kk = sred[0];
            for (int i = 1; i < 4; ++i) if (sred[i] < kk) kk = sred[i];
            sjmin[r] = (int)(kk & 0xffffffffull);
        }
        __syncthreads();
    }
    __syncthreads();

    // indices + perplexity counts
    if (t < 64) {
        const int j = sjmin[t];
        out[IDX_OFF + n0 + t] = (float)j;
        atomicAdd((uint*)ws + 64 + j, 1u);
    }

    // gather codebook rows, loss, stage into tile
    float lsum = 0.f;
    {
        const int r = t & 63, cq = t >> 6;
        const float* wrow = w + ((size_t)sjmin[r] << 8);
        for (int i = 0; i < 16; ++i) {
            const int c0 = (i * 4 + cq) * 4;
            float4 v = *(const float4*)(wrow + c0);
            float d0 = v.x - tile[c0 + 0][r];
            float d1 = v.y - tile[c0 + 1][r];
            float d2 = v.z - tile[c0 + 2][r];
            float d3 = v.w - tile[c0 + 3][r];
            lsum += d0 * d0 + d1 * d1 + d2 * d2 + d3 * d3;
            tile[c0 + 0][r] = v.x;
            tile[c0 + 1][r] = v.y;
            tile[c0 + 2][r] = v.z;
            tile[c0 + 3][r] = v.w;
        }
    }
    __syncthreads();

    // z_q (NCHW) coalesced write
    {
        const int r4 = t & 15, cb = t >> 4;
        for (int i = 0; i < 16; ++i) {
            const int c = i * 16 + cb;
            float4 v = *(const float4*)&tile[c][r4 * 4];
            *(float4*)(out + ZQ_OFF + ((size_t)(b * 256 + c) << 10) + hw0 + r4 * 4) = v;
        }
    }

    // loss reduction
    for (int off = 32; off >= 1; off >>= 1) lsum += __shfl_xor(lsum, off, 64);
    if ((t & 63) == 0) lred[t >> 6] = lsum;
    __syncthreads();
    if (t == 0) atomicAdd(ws, lred[0] + lred[1] + lred[2] + lred[3]);
}

__global__ __launch_bounds__(1024) void vq_fin(float* __restrict__ out,
                                               float* __restrict__ ws) {
    __shared__ float red[16];
    const int t = threadIdx.x;
    const uint cnt = ((const uint*)ws)[64 + t];
    const float e = (float)cnt * (1.0f / 32768.0f);
    float s = e * logf(e + 1e-10f);
    for (int off = 32; off >= 1; off >>= 1) s += __shfl_xor(s, off, 64);
    if ((t & 63) == 0) red[t >> 6] = s;
    __syncthreads();
    if (t == 0) {
        float H = 0.f;
        for (int i = 0; i < 16; ++i) H += red[i];
        out[PPLX_OFF] = expf(-H);
        const float l = ws[0] * (1.0f / 8388608.0f);
        out[0] = l + 0.25f * l;
    }
}

extern "C" void kernel_launch(void* const* d_in, const int* in_sizes, int n_in,
                              void* d_out, int out_size, void* d_ws, size_t ws_size,
                              hipStream_t stream) {
    const float* z = (const float*)d_in[0];   // (32,256,32,32) f32
    const float* w = (const float*)d_in[1];   // (1024,256) f32
    float* out = (float*)d_out;
    float* ws = (float*)d_ws;

    uint* candc = (uint*)((char*)d_ws + WS_CANDC);
    uint* safeflag = (uint*)((char*)d_ws + WS_FLAG);
    ushort* lists = (ushort*)((char*)d_ws + WS_LIST);
    float* w2 = (float*)((char*)d_ws + WS_W2);
    ushort* ebf_l = (ushort*)((char*)d_ws + WS_EBF);

    vq_zero<<<64, 256, 0, stream>>>((uint*)d_ws);
    vq_prep_w2<<<16, 64, 0, stream>>>(w, w2);
    vq_prep_e<<<128, 256, 0, stream>>>(w, ebf_l);
    vq_sweep<<<1024, 256, 0, stream>>>(z, ebf_l, w2, candc, safeflag, lists);
    vq_refine<<<512, 256, 0, stream>>>(z, w, w2, candc, safeflag, lists, out, ws);
    vq_fin<<<1, 1024, 0, stream>>>(out, ws);
}